// Round 1
// baseline (89.403 us; speedup 1.0000x reference)
//
#include <hip/hip_runtime.h>
#include <hip/hip_bf16.h>
#include <math.h>

// ---------------------------------------------------------------------------
// SCF_GRUCell: spatial binning of 400k neighbors -> segment mean (64 bins x 48)
// -> FC(48x3072)+ReLU -> scalar-gate GRU (rt is dead code in the reference).
//
// ws layout (floats):
//   [0,    3072) : bin sums   [64][48]
//   [3072, 3136) : bin counts [64]
//   [3136, 3184) : fsp        [48]
// ---------------------------------------------------------------------------

#define NBINS 64
#define HID 48
#define PAD 49  // LDS row stride: bank = (17*bin + j) % 32 -> full spread

__global__ void zero_ws_kernel(float* ws) {
    int i = blockIdx.x * blockDim.x + threadIdx.x;
    if (i < NBINS * HID + NBINS) ws[i] = 0.0f;
}

__global__ __launch_bounds__(1024) void bin_accum_kernel(
    const float2* __restrict__ loc_others,
    const float*  __restrict__ loc_agent,
    const int*    __restrict__ loc_other_index,
    const float*  __restrict__ hiddens,
    float* __restrict__ ws_sums,   // [64*48]
    float* __restrict__ ws_cnts,   // [64]
    int n)
{
    __shared__ float s_sum[NBINS * PAD];
    __shared__ float s_cnt[NBINS];
    for (int k = threadIdx.x; k < NBINS * PAD; k += blockDim.x) s_sum[k] = 0.0f;
    if (threadIdx.x < NBINS) s_cnt[threadIdx.x] = 0.0f;
    __syncthreads();

    const float ax = loc_agent[0];
    const float ay = loc_agent[1];

    int t = blockIdx.x * blockDim.x + threadIdx.x;
    int stride = gridDim.x * blockDim.x;
    for (int i = t; i < n; i += stride) {
        float2 p = loc_others[i];
        float cx = p.x - ax;
        float cy = p.y - ay;
        float d = sqrtf(cx * cx + cy * cy);
        if (d < 0.5f || d > 40.0f) continue;  // mask

        // dist > 0 guaranteed here (>= 0.5), so safe_dist == d
        float ac = acosf(fminf(fmaxf(cx / d, -1.0f), 1.0f));
        float theta = (cy < 0.0f) ? (6.283185307179586f - ac) : ac;

        float uf = floorf((d - 0.5f) / 4.9375f);           // RADIUS_STEP
        float vf = floorf(theta / 0.7853981633974483f);    // THETA_STEP
        int u = (int)fminf(fmaxf(uf, 0.0f), 7.0f);
        int v = (int)fminf(fmaxf(vf, 0.0f), 7.0f);
        int bin = u * 8 + v;

        int row = loc_other_index[i];
        const float4* hp = (const float4*)(hiddens + (size_t)row * HID);
        float* dst = s_sum + bin * PAD;
        unsafeAtomicAdd(&s_cnt[bin], 1.0f);
#pragma unroll
        for (int k = 0; k < HID / 4; ++k) {
            float4 h = hp[k];
            unsafeAtomicAdd(dst + 4 * k + 0, h.x);
            unsafeAtomicAdd(dst + 4 * k + 1, h.y);
            unsafeAtomicAdd(dst + 4 * k + 2, h.z);
            unsafeAtomicAdd(dst + 4 * k + 3, h.w);
        }
    }
    __syncthreads();

    // Block epilogue: combine private histogram into global accumulators.
    for (int k = threadIdx.x; k < NBINS * HID; k += blockDim.x) {
        int b = k / HID;
        int j = k - b * HID;
        unsafeAtomicAdd(&ws_sums[k], s_sum[b * PAD + j]);
    }
    if (threadIdx.x < NBINS) unsafeAtomicAdd(&ws_cnts[threadIdx.x], s_cnt[threadIdx.x]);
}

__global__ __launch_bounds__(256) void fc_kernel(
    const float* __restrict__ W_fc,    // [48][3072]
    const float* __restrict__ b_fc,    // [48]
    const float* __restrict__ sums,    // [64*48]
    const float* __restrict__ cnts,    // [64]
    float* __restrict__ fsp)           // [48]
{
    int r = blockIdx.x;
    const float* w = W_fc + (size_t)r * (NBINS * HID);
    float partial = 0.0f;
    for (int k = threadIdx.x; k < NBINS * HID; k += 256) {
        int b = k / HID;
        float c = cnts[b];
        float s = sums[k];
        float sp = (c > 1.0f) ? (s / c) : s;
        partial += w[k] * sp;
    }
    // reduce 256 threads = 4 waves
    for (int off = 32; off >= 1; off >>= 1) partial += __shfl_down(partial, off, 64);
    __shared__ float red[4];
    if ((threadIdx.x & 63) == 0) red[threadIdx.x >> 6] = partial;
    __syncthreads();
    if (threadIdx.x == 0) {
        float s = red[0] + red[1] + red[2] + red[3];
        fsp[r] = fmaxf(s + b_fc[r], 0.0f);
    }
}

__global__ void gru_kernel(
    const float* __restrict__ feature_img,  // [1,32,80,80]
    const float* __restrict__ loc_agent,    // [2]
    const float* __restrict__ f_vel,        // [16]
    const float* __restrict__ fsp,          // [48] (ws)
    const float* __restrict__ hidden,       // [48]
    const float* __restrict__ w_iz, const float* __restrict__ w_hz,
    const float* __restrict__ b_iz, const float* __restrict__ b_hz,
    const float* __restrict__ w_in, const float* __restrict__ w_hn,
    const float* __restrict__ b_in, const float* __restrict__ b_hn,
    float* __restrict__ out)                // [48]
{
    int l = threadIdx.x;  // 0..63, one wave
    int u0 = 40 - (int)loc_agent[1];
    int v0 = (int)loc_agent[0];
    int pix = u0 * 80 + v0;

    float pz = 0.0f, pn = 0.0f;
    for (int e = l; e < 96; e += 64) {
        float x;
        if (e < 32)      x = feature_img[e * 6400 + pix];
        else if (e < 48) x = f_vel[e - 32];
        else             x = fsp[e - 48];
        pz += x * w_iz[e];
        pn += x * w_in[e];
    }
    if (l < HID) {
        float h = hidden[l];
        pz += h * w_hz[l];
        pn += h * w_hn[l];
    }
    // butterfly reduce across the 64-lane wave (all lanes get the total)
    for (int off = 32; off >= 1; off >>= 1) {
        pz += __shfl_xor(pz, off, 64);
        pn += __shfl_xor(pn, off, 64);
    }
    float zt = 1.0f / (1.0f + expf(-(pz + b_iz[0] + b_hz[0])));
    float nt = tanhf(pn + b_in[0] + b_hn[0]);
    if (l < HID) out[l] = (1.0f - zt) * nt + zt * hidden[l];
}

extern "C" void kernel_launch(void* const* d_in, const int* in_sizes, int n_in,
                              void* d_out, int out_size, void* d_ws, size_t ws_size,
                              hipStream_t stream) {
    const float* loc_agent       = (const float*)d_in[0];
    const float* loc_others      = (const float*)d_in[1];
    const int*   loc_other_index = (const int*)d_in[2];
    const float* feature_img     = (const float*)d_in[3];
    const float* f_vel           = (const float*)d_in[4];
    const float* hiddens         = (const float*)d_in[5];
    const float* hidden          = (const float*)d_in[6];
    const float* W_fc            = (const float*)d_in[7];
    const float* b_fc            = (const float*)d_in[8];
    // d_in[9..12] = weight_ir / weight_hr / bias_ir / bias_hr : dead code
    const float* w_iz            = (const float*)d_in[13];
    const float* w_hz            = (const float*)d_in[14];
    const float* b_iz            = (const float*)d_in[15];
    const float* b_hz            = (const float*)d_in[16];
    const float* w_in            = (const float*)d_in[17];
    const float* w_hn            = (const float*)d_in[18];
    const float* b_in            = (const float*)d_in[19];
    const float* b_hn            = (const float*)d_in[20];

    float* ws   = (float*)d_ws;
    float* sums = ws;            // 3072
    float* cnts = ws + 3072;     // 64
    float* fsp  = ws + 3136;     // 48
    float* out  = (float*)d_out;

    int n = in_sizes[2];  // 400000 neighbors

    hipLaunchKernelGGL(zero_ws_kernel, dim3(13), dim3(256), 0, stream, ws);
    hipLaunchKernelGGL(bin_accum_kernel, dim3(256), dim3(1024), 0, stream,
                       (const float2*)loc_others, loc_agent, loc_other_index,
                       hiddens, sums, cnts, n);
    hipLaunchKernelGGL(fc_kernel, dim3(48), dim3(256), 0, stream,
                       W_fc, b_fc, sums, cnts, fsp);
    hipLaunchKernelGGL(gru_kernel, dim3(1), dim3(64), 0, stream,
                       feature_img, loc_agent, f_vel, fsp, hidden,
                       w_iz, w_hz, b_iz, b_hz, w_in, w_hn, b_in, b_hn, out);
}